// Round 2
// baseline (549.228 us; speedup 1.0000x reference)
//
#include <hip/hip_runtime.h>
#include <hip/hip_bf16.h>

#define B_   32
#define C_   64
#define H_   96
#define W_   96
#define K_   32
#define R_   13
#define HO_  84
#define WO_  84
#define HW_  (H_*W_)      // 9216
#define OHW_ (HO_*WO_)    // 7056
#define CRR_ (C_*R_*R_)   // 10816
#define RR_  (R_*R_)      // 169

#define TILE_ 16
#define PW_   28          // patch height/width = TILE_+12
#define NPIX_ (PW_*PW_)   // 784
#define XS_BYTES (NPIX_*128)           // 100352: [pixel][64c] bf16, slot-swizzled
#define LDS_BYTES XS_BYTES

typedef unsigned int u32;
typedef unsigned short u16;
typedef __attribute__((ext_vector_type(16))) float f32x16;
typedef __attribute__((ext_vector_type(4))) u32 u32x4;

static __device__ __forceinline__ u16 f2bf(float v){
    __hip_bfloat16 h = __float2bfloat16(v);  // RNE
    return *reinterpret_cast<u16*>(&h);
}

// D = A*B + D  (32x32x16 bf16)
#define MFMA(acc, a, b) asm("v_mfma_f32_32x32x16_bf16 %0, %1, %2, %0" \
                            : "+v"(acc) : "v"(a), "v"(b))

// ---------------- k1: y-norms + swizzled bf16 prototype tensor -------------
// u_g layout: [ij][k][128B row]; byte in row = ((c>>3)^(k&7))*16 + (c&7)*2
__global__ void k_prep_y(const float* __restrict__ y, unsigned char* __restrict__ u_g){
    int k = blockIdx.x, tid = threadIdx.x;
    const float* yk = y + (size_t)k * CRR_;
    float ss = 0.f;
    for (int idx = tid; idx < CRR_; idx += 256){ float v = yk[idx]; ss += v*v; }
    for (int off = 32; off; off >>= 1) ss += __shfl_down(ss, off);
    __shared__ float red[4];
    if ((tid & 63) == 0) red[tid >> 6] = ss;
    __syncthreads();
    float inv = 1.f / fmaxf(sqrtf(red[0]+red[1]+red[2]+red[3]), 1e-9f);

    int c = tid & 63, grp = tid >> 6;                 // 64 c-lanes x 4 ij-groups
    int swz = ((((c >> 3) ^ (k & 7)) << 4) | ((c & 7) << 1));
    for (int base = 0; base < RR_; base += 4){
        int ij = base + grp;
        if (ij < RR_){
            float v = yk[c*RR_ + ij] * inv;
            *(u16*)(u_g + (size_t)ij*4096 + k*128 + swz) = f2bf(v);
        }
    }
}

// ---------------- k2: s[b,y,x] = sum_c x^2 (fp32 exact) --------------------
__global__ void k_sq(const float* __restrict__ x, float* __restrict__ s){
    int idx = blockIdx.x*256 + threadIdx.x;           // < 294912 exact
    int b = idx / HW_, r = idx % HW_;
    const float* xb = x + (size_t)b * C_ * HW_;
    float acc = 0.f;
    #pragma unroll
    for (int c = 0; c < C_; ++c){ float v = xb[(size_t)c*HW_ + r]; acc += v*v; }
    s[idx] = acc;
}

// ---------------- k3: inv_xn = 1/max(sqrt(13x13 box sum), eps) -------------
__global__ void k_inv(const float* __restrict__ s, float* __restrict__ inv_xn){
    int idx = blockIdx.x*256 + threadIdx.x;           // < 225792 exact
    int b = idx / OHW_, r = idx % OHW_;
    int oh = r / WO_, ow = r % WO_;
    const float* sb = s + (size_t)b*HW_ + oh*W_ + ow;
    float acc = 0.f;
    for (int i = 0; i < R_; ++i){
        #pragma unroll
        for (int j = 0; j < R_; ++j) acc += sb[i*W_ + j];
    }
    inv_xn[idx] = 1.f / fmaxf(sqrtf(acc), 1e-9f);
}

// ---------------- k_main: fused cosine-similarity conv ---------------------
// Block: b x 16x16 output tile, 256 thr (4 waves). Wave w owns output rows
// oy+4w..oy+4w+3 as two B-frags (2 rows x 16 cols each). A (prototype slice)
// streams from global (L1/L2-resident, 4KB/tap), prefetched 1 tap ahead.
// NO barriers in the 169-tap loop.
__launch_bounds__(256, 1)
__global__ void k_main(const float* __restrict__ x, const unsigned char* __restrict__ u_g,
                       const float* __restrict__ inv_xn, float* __restrict__ out){
    extern __shared__ unsigned char lds[];
    unsigned char* xs = lds;

    int bb = blockIdx.x;
    int b  = bb / 36;
    int tt = bb % 36;
    int oy = (tt / 6) * TILE_;
    int ox = (tt % 6) * TILE_;

    int tid  = threadIdx.x;
    int lane = tid & 63;
    int wv   = tid >> 6;        // 0..3
    int ks   = lane >> 5;       // k-half of MFMA operands
    int rb   = (lane >> 4) & 1; // row within a frag's 2-row strip
    int cx   = lane & 15;       // col
    int kpr  = lane & 31;       // prototype row for A-frag

    // ---- stage x patch: fp32 global -> bf16 LDS, swizzled, b128 writes ----
    const float* xb = x + (size_t)b * C_ * HW_;
    for (int p = tid; p < NPIX_; p += 256){
        int py = p / PW_, px = p % PW_;
        int gy = oy + py; if (gy > H_-1) gy = H_-1;   // clamp: only feeds invalid outputs
        int gx = ox + px; if (gx > W_-1) gx = W_-1;
        const float* src = xb + gy*W_ + gx;
        unsigned char* dst = xs + p*128;
        int psw = p & 7;
        #pragma unroll
        for (int sl = 0; sl < 8; ++sl){
            int c0 = sl*8;
            u32 w0 = f2bf(src[(size_t)(c0+0)*HW_]) | ((u32)f2bf(src[(size_t)(c0+1)*HW_]) << 16);
            u32 w1 = f2bf(src[(size_t)(c0+2)*HW_]) | ((u32)f2bf(src[(size_t)(c0+3)*HW_]) << 16);
            u32 w2 = f2bf(src[(size_t)(c0+4)*HW_]) | ((u32)f2bf(src[(size_t)(c0+5)*HW_]) << 16);
            u32 w3 = f2bf(src[(size_t)(c0+6)*HW_]) | ((u32)f2bf(src[(size_t)(c0+7)*HW_]) << 16);
            u32x4 q = {w0, w1, w2, w3};
            *(u32x4*)(dst + ((sl ^ psw) << 4)) = q;
        }
    }
    __syncthreads();   // the ONLY barrier

    f32x16 acc0 = {}, acc1 = {};
    int baseA = (kpr << 7) ^ ((ks ^ (kpr & 7)) << 4);   // loop-invariant A lane offset
    int pb0 = (4*wv + rb) * PW_ + cx;                   // frag0: rows 4w+0,4w+1
    // frag1 = pb0 + 2*PW_                              // frag1: rows 4w+2,4w+3

#define LOADA(dst, ijv, cc) dst = *(const u32x4*)(u_g + (size_t)(ijv)*4096 + (baseA ^ ((cc) << 5)))

    u32x4 A0, A1, A2, A3;
    LOADA(A0, 0, 0); LOADA(A1, 0, 1); LOADA(A2, 0, 2); LOADA(A3, 0, 3);

    int ij = 0;
    for (int i = 0; i < R_; ++i){
        int prow = pb0 + i*PW_;
        #pragma unroll
        for (int jx = 0; jx < R_; ++jx, ++ij){
            int nij = ij + 1; if (nij > RR_-1) nij = RR_-1;   // last prefetch re-reads slice 168
            u32x4 N0, N1, N2, N3;
            LOADA(N0, nij, 0); LOADA(N1, nij, 1); LOADA(N2, nij, 2); LOADA(N3, nij, 3);

            int p0 = prow + jx;
            int p1 = p0 + 2*PW_;
            int b0 = (p0 << 7) ^ ((ks ^ (p0 & 7)) << 4);
            int b1 = (p1 << 7) ^ ((ks ^ (p1 & 7)) << 4);
            u32x4 bv;
            bv = *(const u32x4*)(xs + (b0      )); MFMA(acc0, A0, bv);
            bv = *(const u32x4*)(xs + (b1      )); MFMA(acc1, A0, bv);
            bv = *(const u32x4*)(xs + (b0 ^ 32 )); MFMA(acc0, A1, bv);
            bv = *(const u32x4*)(xs + (b1 ^ 32 )); MFMA(acc1, A1, bv);
            bv = *(const u32x4*)(xs + (b0 ^ 64 )); MFMA(acc0, A2, bv);
            bv = *(const u32x4*)(xs + (b1 ^ 64 )); MFMA(acc1, A2, bv);
            bv = *(const u32x4*)(xs + (b0 ^ 96 )); MFMA(acc0, A3, bv);
            bv = *(const u32x4*)(xs + (b1 ^ 96 )); MFMA(acc1, A3, bv);

            A0 = N0; A1 = N1; A2 = N2; A3 = N3;
        }
    }

    // ---- epilogue: relu(num) * 1/||x_win||, D layout col=lane&31,
    // row = (r&3) + 8*(r>>2) + 4*(lane>>5) ----
    int ow = ox + cx;
    float* ob = out + (size_t)b*K_*OHW_ + ow;
    #pragma unroll
    for (int f = 0; f < 2; ++f){
        int oh = oy + 4*wv + rb + 2*f;
        bool valid = (oh < HO_) && (ow < WO_);
        float inv = 0.f;
        if (valid) inv = inv_xn[(size_t)b*OHW_ + oh*WO_ + ow];
        const f32x16& acc = f ? acc1 : acc0;
        #pragma unroll
        for (int r = 0; r < 16; ++r){
            int kp = (r & 3) + 8*(r >> 2) + 4*ks;
            if (valid) ob[(size_t)kp*OHW_ + oh*WO_] = fmaxf(acc[r], 0.f) * inv;
        }
    }
}

extern "C" void kernel_launch(void* const* d_in, const int* in_sizes, int n_in,
                              void* d_out, int out_size, void* d_ws, size_t ws_size,
                              hipStream_t stream) {
    const float* x = (const float*)d_in[0];
    const float* y = (const float*)d_in[1];
    float* out = (float*)d_out;
    unsigned char* ws = (unsigned char*)d_ws;

    unsigned char* u_g   = ws;                                   // 692224 B
    float*         s     = (float*)(ws + 692224);                // 1179648 B
    float*         invxn = (float*)(ws + 692224 + 1179648);      // 903168 B

    k_prep_y<<<K_, 256, 0, stream>>>(y, u_g);
    k_sq<<<(B_*HW_)/256, 256, 0, stream>>>(x, s);
    k_inv<<<(B_*OHW_)/256, 256, 0, stream>>>(s, invxn);

    hipFuncSetAttribute(reinterpret_cast<const void*>(k_main),
                        hipFuncAttributeMaxDynamicSharedMemorySize, LDS_BYTES);
    k_main<<<B_*36, 256, LDS_BYTES, stream>>>(x, u_g, invxn, out);
}

// Round 3
// 248.971 us; speedup vs baseline: 2.2060x; 2.2060x over previous
//
#include <hip/hip_runtime.h>
#include <hip/hip_bf16.h>

#define B_   32
#define C_   64
#define H_   96
#define W_   96
#define K_   32
#define R_   13
#define HO_  84
#define WO_  84
#define HW_  (H_*W_)      // 9216
#define OHW_ (HO_*WO_)    // 7056
#define CRR_ (C_*R_*R_)   // 10816
#define RR_  (R_*R_)      // 169

#define TILE_ 16
#define PW_   28          // patch height/width = TILE_+12
#define NPIX_ (PW_*PW_)   // 784
#define REG_BYTES (NPIX_*16)           // 12544 per (kstep,khalf) region
#define LDS_BYTES (4*REG_BYTES)        // 50176: 32ch/pass, pixel-major, linear

typedef unsigned int u32;
typedef unsigned short u16;
typedef __attribute__((ext_vector_type(16))) float f32x16;
typedef __attribute__((ext_vector_type(4))) u32 u32x4;

static __device__ __forceinline__ u16 f2bf(float v){
    __hip_bfloat16 h = __float2bfloat16(v);  // RNE
    return *reinterpret_cast<u16*>(&h);
}

// D = A*B + D  (32x32x16 bf16)
#define MFMA(acc, a, b) asm("v_mfma_f32_32x32x16_bf16 %0, %1, %2, %0" \
                            : "+v"(acc) : "v"(a), "v"(b))

// ---------------- k1: y-norms + bf16 prototype tensor ----------------------
// u_g layout: [ij][kq(4)][k(32)][half(2)][16B]  (4KB per ij slice)
// A-frag load for kstep kq: lane l reads ij*4096 + kq*1024 + (l&31)*32 + (l>>5)*16
__global__ void k_prep_y(const float* __restrict__ y, unsigned char* __restrict__ u_g){
    int k = blockIdx.x, tid = threadIdx.x;
    const float* yk = y + (size_t)k * CRR_;
    float ss = 0.f;
    for (int idx = tid; idx < CRR_; idx += 256){ float v = yk[idx]; ss += v*v; }
    for (int off = 32; off; off >>= 1) ss += __shfl_down(ss, off);
    __shared__ float red[4];
    if ((tid & 63) == 0) red[tid >> 6] = ss;
    __syncthreads();
    float inv = 1.f / fmaxf(sqrtf(red[0]+red[1]+red[2]+red[3]), 1e-9f);

    int c = tid & 63, grp = tid >> 6;                 // 64 c-lanes x 4 ij-groups
    int off = ((c >> 4) << 10) | (k << 5) | (((c >> 3) & 1) << 4) | ((c & 7) << 1);
    for (int base = 0; base < RR_; base += 4){
        int ij = base + grp;
        if (ij < RR_){
            float v = yk[c*RR_ + ij] * inv;
            *(u16*)(u_g + (size_t)ij*4096 + off) = f2bf(v);
        }
    }
}

// ---------------- k2: s[b,y,x] = sum_c x^2 (fp32 exact) --------------------
__global__ void k_sq(const float* __restrict__ x, float* __restrict__ s){
    int idx = blockIdx.x*256 + threadIdx.x;           // < 294912 exact
    int b = idx / HW_, r = idx % HW_;
    const float* xb = x + (size_t)b * C_ * HW_;
    float acc = 0.f;
    #pragma unroll
    for (int c = 0; c < C_; ++c){ float v = xb[(size_t)c*HW_ + r]; acc += v*v; }
    s[idx] = acc;
}

// ---------------- k3: inv_xn = 1/max(sqrt(13x13 box sum), eps) -------------
__global__ void k_inv(const float* __restrict__ s, float* __restrict__ inv_xn){
    int idx = blockIdx.x*256 + threadIdx.x;           // < 225792 exact
    int b = idx / OHW_, r = idx % OHW_;
    int oh = r / WO_, ow = r % WO_;
    const float* sb = s + (size_t)b*HW_ + oh*W_ + ow;
    float acc = 0.f;
    for (int i = 0; i < R_; ++i){
        #pragma unroll
        for (int j = 0; j < R_; ++j) acc += sb[i*W_ + j];
    }
    inv_xn[idx] = 1.f / fmaxf(sqrtf(acc), 1e-9f);
}

// ---------------- k_main: fused cosine-similarity conv ---------------------
// Block: b x 16x16 output tile, 256 thr (4 waves). TWO channel passes (32ch
// each) so LDS = 50KB -> 3 blocks/CU = 3 waves/SIMD. acc persists across
// passes. Barrier-free 169-tap loop; A streams from global (L1-resident),
// prefetched 1 tap ahead. LDS pixel-major: contiguous 256B per 16-lane group.
__launch_bounds__(256, 3)
__global__ void k_main(const float* __restrict__ x, const unsigned char* __restrict__ u_g,
                       const float* __restrict__ inv_xn, float* __restrict__ out){
    extern __shared__ unsigned char lds[];
    unsigned char* xs = lds;

    int bb = blockIdx.x;
    int b  = bb / 36;
    int tt = bb % 36;
    int oy = (tt / 6) * TILE_;
    int ox = (tt % 6) * TILE_;

    int tid  = threadIdx.x;
    int lane = tid & 63;
    int wv   = tid >> 6;        // 0..3
    int ks   = lane >> 5;       // k-half of MFMA operands
    int rb   = (lane >> 4) & 1; // row within a frag's 2-row strip
    int cx   = lane & 15;       // col
    int kpr  = lane & 31;       // prototype row for A-frag

    const float* xb = x + (size_t)b * C_ * HW_;
    int aoff = (kpr << 5) + (ks << 4);                  // A lane offset within 1KB kq block
    int pb0 = (4*wv + rb) * PW_ + cx;                   // frag0 pixel; frag1 = +2*PW_

    f32x16 acc0 = {}, acc1 = {};

#define LOADA(ijv, kq) (*(const u32x4*)(u_g + (size_t)(ijv)*4096 + ((kq) << 10) + aoff))

    for (int pass = 0; pass < 2; ++pass){
        if (pass) __syncthreads();         // pass0 reads done before overwrite
        // ---- stage 32 channels: fp32 global -> bf16 LDS, pixel-major ----
        int cbase = pass << 5;
        for (int p = tid; p < NPIX_; p += 256){
            int py = p / PW_, px = p % PW_;
            int gy = oy + py; if (gy > H_-1) gy = H_-1;   // clamp feeds only invalid outputs
            int gx = ox + px; if (gx > W_-1) gx = W_-1;
            const float* src = xb + (size_t)cbase*HW_ + gy*W_ + gx;
            #pragma unroll
            for (int q = 0; q < 4; ++q){                  // q = kstep*2 + half
                int c0 = q*8;
                u32 w0 = f2bf(src[(size_t)(c0+0)*HW_]) | ((u32)f2bf(src[(size_t)(c0+1)*HW_]) << 16);
                u32 w1 = f2bf(src[(size_t)(c0+2)*HW_]) | ((u32)f2bf(src[(size_t)(c0+3)*HW_]) << 16);
                u32 w2 = f2bf(src[(size_t)(c0+4)*HW_]) | ((u32)f2bf(src[(size_t)(c0+5)*HW_]) << 16);
                u32 w3 = f2bf(src[(size_t)(c0+6)*HW_]) | ((u32)f2bf(src[(size_t)(c0+7)*HW_]) << 16);
                u32x4 v = {w0, w1, w2, w3};
                *(u32x4*)(xs + q*REG_BYTES + p*16) = v;
            }
        }
        __syncthreads();

        const unsigned char* r0 = xs + ks*REG_BYTES;        // kstep 0 (this pass)
        const unsigned char* r1 = xs + (2+ks)*REG_BYTES;    // kstep 1
        int kq0 = pass*2, kq1 = pass*2 + 1;

        u32x4 A0 = LOADA(0, kq0), A1 = LOADA(0, kq1);
        int ij = 0;
        for (int i = 0; i < R_; ++i){
            int prow = pb0 + i*PW_;
            #pragma unroll
            for (int jx = 0; jx < R_; ++jx, ++ij){
                int nij = ij + 1; if (nij > RR_-1) nij = RR_-1;
                u32x4 N0 = LOADA(nij, kq0), N1 = LOADA(nij, kq1);

                int p0 = prow + jx;
                int p1 = p0 + 2*PW_;
                u32x4 bv;
                bv = *(const u32x4*)(r0 + p0*16); MFMA(acc0, A0, bv);
                bv = *(const u32x4*)(r0 + p1*16); MFMA(acc1, A0, bv);
                bv = *(const u32x4*)(r1 + p0*16); MFMA(acc0, A1, bv);
                bv = *(const u32x4*)(r1 + p1*16); MFMA(acc1, A1, bv);
                A0 = N0; A1 = N1;
            }
        }
    }

    // ---- epilogue: relu(num) * 1/||x_win||; D: col=lane&31,
    // row = (r&3) + 8*(r>>2) + 4*(lane>>5) ----
    int ow = ox + cx;
    float* ob = out + (size_t)b*K_*OHW_ + ow;
    #pragma unroll
    for (int f = 0; f < 2; ++f){
        int oh = oy + 4*wv + rb + 2*f;
        bool valid = (oh < HO_) && (ow < WO_);
        float inv = 0.f;
        if (valid) inv = inv_xn[(size_t)b*OHW_ + oh*WO_ + ow];
        const f32x16& acc = f ? acc1 : acc0;
        #pragma unroll
        for (int r = 0; r < 16; ++r){
            int kp = (r & 3) + 8*(r >> 2) + 4*ks;
            if (valid) ob[(size_t)kp*OHW_ + oh*WO_] = fmaxf(acc[r], 0.f) * inv;
        }
    }
}

extern "C" void kernel_launch(void* const* d_in, const int* in_sizes, int n_in,
                              void* d_out, int out_size, void* d_ws, size_t ws_size,
                              hipStream_t stream) {
    const float* x = (const float*)d_in[0];
    const float* y = (const float*)d_in[1];
    float* out = (float*)d_out;
    unsigned char* ws = (unsigned char*)d_ws;

    unsigned char* u_g   = ws;                                   // 692224 B
    float*         s     = (float*)(ws + 692224);                // 1179648 B
    float*         invxn = (float*)(ws + 692224 + 1179648);      // 903168 B

    k_prep_y<<<K_, 256, 0, stream>>>(y, u_g);
    k_sq<<<(B_*HW_)/256, 256, 0, stream>>>(x, s);
    k_inv<<<(B_*OHW_)/256, 256, 0, stream>>>(s, invxn);

    k_main<<<B_*36, 256, LDS_BYTES, stream>>>(x, u_g, invxn, out);
}